// Round 5
// baseline (412.666 us; speedup 1.0000x reference)
//
#include <hip/hip_runtime.h>
#include <math.h>

typedef float f32x4 __attribute__((ext_vector_type(4)));
typedef __bf16 bf16x2 __attribute__((ext_vector_type(2)));
typedef __bf16 bf16x4 __attribute__((ext_vector_type(4)));
typedef __bf16 bf16x8 __attribute__((ext_vector_type(8)));

// ---------------------------------------------------------------------------
// GAT 2-layer forward.
// GEMMs: split-bf16 MFMA. A staged in LDS (dbuf, 16KB); B hi/lo read directly
// from L2 into registers (no LDS round-trip). Fused el/er epilogue via
// quarter-tiles (wave q's strip == heads {2q,2q+1}). agg1 emits pre-split
// hh/hl bf16 so layer-2 GEMM stages A with global_load_lds width 16.
// ---------------------------------------------------------------------------

__global__ void hist_kernel(const int* __restrict__ dst, int* __restrict__ cnt, int E) {
    int e = blockIdx.x * blockDim.x + threadIdx.x;
    if (e < E) atomicAdd(&cnt[dst[e]], 1);
}

__global__ __launch_bounds__(256) void scan_blk(const int* __restrict__ cnt,
                                                int* __restrict__ incl,
                                                int* __restrict__ bsum, int n) {
    __shared__ int sd[256];
    const int t = threadIdx.x;
    int i = blockIdx.x * 256 + t;
    int v = (i < n) ? cnt[i] : 0;
    sd[t] = v;
    __syncthreads();
#pragma unroll
    for (int off = 1; off < 256; off <<= 1) {
        int x = (t >= off) ? sd[t - off] : 0;
        __syncthreads();
        sd[t] += x;
        __syncthreads();
    }
    if (i < n) incl[i] = sd[t];
    if (t == 255) bsum[blockIdx.x] = sd[255];
}

__global__ __launch_bounds__(256) void scan_top(const int* __restrict__ bsum,
                                                int* __restrict__ boff, int nb) {
    __shared__ int sd[256];
    const int t = threadIdx.x;
    int v = (t < nb) ? bsum[t] : 0;
    sd[t] = v;
    __syncthreads();
#pragma unroll
    for (int off = 1; off < 256; off <<= 1) {
        int x = (t >= off) ? sd[t - off] : 0;
        __syncthreads();
        sd[t] += x;
        __syncthreads();
    }
    if (t < nb) boff[t] = sd[t] - v;
}

__global__ void scan_fix(const int* __restrict__ incl, const int* __restrict__ boff,
                         const int* __restrict__ cnt, int* __restrict__ row_ptr,
                         int* __restrict__ cursor, int n) {
    int i = blockIdx.x * blockDim.x + threadIdx.x;
    if (i >= n) return;
    int total = incl[i] + boff[i >> 8];
    row_ptr[i + 1] = total;
    cursor[i] = total - cnt[i];
    if (i == 0) row_ptr[0] = 0;
}

__global__ void fill_kernel(const int* __restrict__ src, const int* __restrict__ dst,
                            int* __restrict__ cursor, int* __restrict__ ssrc,
                            int* __restrict__ sdst, int E) {
    int e = blockIdx.x * blockDim.x + threadIdx.x;
    if (e < E) {
        int d = dst[e];
        int pos = atomicAdd(&cursor[d], 1);
        ssrc[pos] = src[e];
        sdst[pos] = d;
    }
}

// W[K][N] fp32 -> Wt_hi/Wt_lo[N][K] bf16 (transposed, split)
__global__ void split_w_kernel(const float* __restrict__ W, __bf16* __restrict__ Wth,
                               __bf16* __restrict__ Wtl, int K, int N) {
    int idx = blockIdx.x * blockDim.x + threadIdx.x;
    if (idx >= K * N) return;
    int k = idx / N, n = idx % N;
    float x = W[idx];
    __bf16 h = (__bf16)x;
    __bf16 l = (__bf16)(x - (float)h);
    Wth[(size_t)n * K + k] = h;
    Wtl[(size_t)n * K + k] = l;
}

// ---------------------------------------------------------------------------
// Split-bf16 MFMA GEMM + fused el/er epilogue.
// FP32A=true : A fp32, reg-staged with in-flight hi/lo split (layer 1).
// FP32A=false: A pre-split bf16 (Ahg/Alg), staged via global_load_lds (layer 2).
// B hi/lo: direct global->register bf16x8 loads (L2-resident, no LDS).
// ---------------------------------------------------------------------------
template <int BN, int NREP, bool FP32A>
__global__ __launch_bounds__(256, 2) void gemm_fused(
    const float* __restrict__ Af, const __bf16* __restrict__ Ahg,
    const __bf16* __restrict__ Alg, const __bf16* __restrict__ Bth,
    const __bf16* __restrict__ Btl, const float* __restrict__ al,
    const float* __restrict__ ar, __bf16* __restrict__ featb,
    float* __restrict__ el, float* __restrict__ er, int M, int K) {
    constexpr int WN = NREP * 16;  // per-wave col strip; BN == 4*WN
    constexpr int D = BN / 8;      // head dim

    struct StageT {
        __bf16 Ah[2][64][32];  // 8KB (dbuf)
        __bf16 Al[2][64][32];  // 8KB
    };
    union Smem {
        StageT s;
        float ctile[64][WN + 1];  // quarter-tile epilogue scratch
    };
    __shared__ __align__(16) Smem u;

    const int t = threadIdx.x;
    const int lane = t & 63;
    const int wid = t >> 6;
    const int row0 = blockIdx.x * 64;
    const int colw = wid * WN;
    const int fr = lane & 15;
    const int kg = (lane >> 4) * 8;

    auto stageA = [&](int p, int k0) {
        if constexpr (FP32A) {
#pragma unroll
            for (int pp = 0; pp < 2; ++pp) {
                int idx = t + pp * 256;
                int r = idx >> 3;
                int c4 = (idx & 7) * 4;
                int gr = row0 + r;
                if (gr >= M) gr = M - 1;
                float4 v = *(const float4*)&Af[(size_t)gr * K + k0 + c4];
                __bf16 h0 = (__bf16)v.x, h1 = (__bf16)v.y, h2 = (__bf16)v.z,
                       h3 = (__bf16)v.w;
                bf16x4 hv = {h0, h1, h2, h3};
                bf16x4 lv = {(__bf16)(v.x - (float)h0), (__bf16)(v.y - (float)h1),
                             (__bf16)(v.z - (float)h2), (__bf16)(v.w - (float)h3)};
                *(bf16x4*)&u.s.Ah[p][r][c4] = hv;
                *(bf16x4*)&u.s.Al[p][r][c4] = lv;
            }
        } else {
            // linear: lds byte offset of [p][t>>2][(t&3)*8] == p*4096 + t*16
            int r = t >> 2;
            int c = (t & 3) * 8;
            int gr = row0 + r;
            if (gr >= M) gr = M - 1;
            __builtin_amdgcn_global_load_lds(
                (const __attribute__((address_space(1))) void*)&Ahg[(size_t)gr * K + k0 + c],
                (__attribute__((address_space(3))) void*)&u.s.Ah[p][r][c], 16, 0, 0);
            __builtin_amdgcn_global_load_lds(
                (const __attribute__((address_space(1))) void*)&Alg[(size_t)gr * K + k0 + c],
                (__attribute__((address_space(3))) void*)&u.s.Al[p][r][c], 16, 0, 0);
        }
    };

    f32x4 acc[4][NREP] = {};

    stageA(0, 0);
    __syncthreads();

    int p = 0;
    for (int k0 = 0; k0 < K; k0 += 32) {
        // ---- B frags: direct global->reg (L2-resident) ----
        bf16x8 bh[NREP], bl[NREP];
#pragma unroll
        for (int n = 0; n < NREP; ++n) {
            size_t boff = (size_t)(colw + n * 16 + fr) * K + k0 + kg;
            bh[n] = *(const bf16x8*)&Bth[boff];
            bl[n] = *(const bf16x8*)&Btl[boff];
        }
        // ---- prefetch next A tile into other buffer ----
        if (k0 + 32 < K) stageA(p ^ 1, k0 + 32);
        // ---- A frags from LDS ----
        bf16x8 ah[4], alv[4];
#pragma unroll
        for (int m = 0; m < 4; ++m) {
            ah[m] = *(const bf16x8*)&u.s.Ah[p][fr + m * 16][kg];
            alv[m] = *(const bf16x8*)&u.s.Al[p][fr + m * 16][kg];
        }
#pragma unroll
        for (int m = 0; m < 4; ++m)
#pragma unroll
            for (int n = 0; n < NREP; ++n) {
                acc[m][n] = __builtin_amdgcn_mfma_f32_16x16x32_bf16(ah[m], bh[n], acc[m][n], 0, 0, 0);
                acc[m][n] = __builtin_amdgcn_mfma_f32_16x16x32_bf16(alv[m], bh[n], acc[m][n], 0, 0, 0);
                acc[m][n] = __builtin_amdgcn_mfma_f32_16x16x32_bf16(ah[m], bl[n], acc[m][n], 0, 0, 0);
            }
        __syncthreads();
        p ^= 1;
    }

    // ---- epilogue part 1: bf16 feat stores ----
#pragma unroll
    for (int m = 0; m < 4; ++m) {
        int rbase = row0 + m * 16 + (lane >> 4) * 4;
#pragma unroll
        for (int n = 0; n < NREP; ++n) {
            int col = colw + n * 16 + fr;
#pragma unroll
            for (int i = 0; i < 4; ++i) {
                int r = rbase + i;
                if (r < M) featb[(size_t)r * BN + col] = (__bf16)acc[m][n][i];
            }
        }
    }

    // ---- epilogue part 2: el/er via quarter-tiles (wave q == heads 2q,2q+1) ----
#pragma unroll
    for (int q = 0; q < 4; ++q) {
        __syncthreads();
        if (wid == q) {
#pragma unroll
            for (int m = 0; m < 4; ++m) {
                int rb = m * 16 + (lane >> 4) * 4;
#pragma unroll
                for (int n = 0; n < NREP; ++n) {
                    int lc = n * 16 + fr;
#pragma unroll
                    for (int i = 0; i < 4; ++i) u.ctile[rb + i][lc] = acc[m][n][i];
                }
            }
        }
        __syncthreads();
        if (t < 128) {
            int r = t & 63;
            int hh = t >> 6;
            int h = q * 2 + hh;
            float sl = 0.f, sr = 0.f;
#pragma unroll
            for (int d = 0; d < D; ++d) {
                float v = u.ctile[r][hh * D + d];
                sl += v * al[h * D + d];
                sr += v * ar[h * D + d];
            }
            int gr = row0 + r;
            if (gr < M) {
                el[(size_t)gr * 8 + h] = sl;
                er[(size_t)gr * 8 + h] = sr;
            }
        }
    }
}

__device__ __forceinline__ float leaky02(float x) { return x > 0.f ? x : 0.2f * x; }

// edge-parallel raw scores (CSR order): pe[pos][8] = leaky(el[s]+er[d])
__global__ void edge_score_kernel(const int* __restrict__ ssrc, const int* __restrict__ sdst,
                                  const float* __restrict__ el, const float* __restrict__ er,
                                  float* __restrict__ pe, int E) {
    int pos = blockIdx.x * blockDim.x + threadIdx.x;
    if (pos >= E) return;
    int s = ssrc[pos], d = sdst[pos];
    float4 l0 = *(const float4*)&el[(size_t)s * 8];
    float4 l1 = *(const float4*)&el[(size_t)s * 8 + 4];
    float4 r0 = *(const float4*)&er[(size_t)d * 8];
    float4 r1 = *(const float4*)&er[(size_t)d * 8 + 4];
    float4 o0 = {leaky02(l0.x + r0.x), leaky02(l0.y + r0.y),
                 leaky02(l0.z + r0.z), leaky02(l0.w + r0.w)};
    float4 o1 = {leaky02(l1.x + r1.x), leaky02(l1.y + r1.y),
                 leaky02(l1.z + r1.z), leaky02(l1.w + r1.w)};
    *(float4*)&pe[(size_t)pos * 8] = o0;
    *(float4*)&pe[(size_t)pos * 8 + 4] = o1;
}

// ---------------------------------------------------------------------------
// Edge-softmax aggregation, one wave per dst node. H=8. Phase-B 4x unrolled.
// MODE 0 (D=32): outh/outl = split-bf16 ELU(sum)  (feeds layer-2 GEMM A)
// MODE 1 (D=40): outf[n,40] = head-mean (final output)
// ---------------------------------------------------------------------------
template <int D, int MODE>
__global__ __launch_bounds__(256) void gat_aggregate(
    const __bf16* __restrict__ featb, const float* __restrict__ pe,
    const int* __restrict__ row_ptr, const int* __restrict__ ssrc,
    __bf16* __restrict__ outh, __bf16* __restrict__ outl,
    float* __restrict__ outf, int N) {
    constexpr int HD = 8 * D;
    constexpr int TAIL = HD - 256;
    __shared__ float red[4][MODE ? HD : 1];

    const int wid = threadIdx.x >> 6;
    const int lane = threadIdx.x & 63;
    const int n = blockIdx.x * 4 + wid;
    if (n >= N) return;

    const int beg = row_ptr[n];
    const int end = row_ptr[n + 1];
    const int hl = lane & 7;
    const int sl = lane >> 3;

    // ---- phase A: per-head max, then sum(exp) ----
    float m_l = -INFINITY;
    for (int idx = beg + sl; idx < end; idx += 8)
        m_l = fmaxf(m_l, pe[(size_t)idx * 8 + hl]);
    m_l = fmaxf(m_l, __shfl_xor(m_l, 8));
    m_l = fmaxf(m_l, __shfl_xor(m_l, 16));
    m_l = fmaxf(m_l, __shfl_xor(m_l, 32));
    float s_l = 0.f;
    for (int idx = beg + sl; idx < end; idx += 8)
        s_l += __expf(pe[(size_t)idx * 8 + hl] - m_l);
    s_l += __shfl_xor(s_l, 8);
    s_l += __shfl_xor(s_l, 16);
    s_l += __shfl_xor(s_l, 32);
    const float si_l = 1.0f / (s_l + 1e-9f);

    int hg[2], ht = 0;
#pragma unroll
    for (int g = 0; g < 2; ++g) hg[g] = (128 * g + 2 * lane) / D;
    if (TAIL) ht = (256 + lane) / D;

    // ---- phase B: accumulate alpha * featb[src], 4x unrolled ----
    float acc[2][2] = {};
    float acct = 0.f;
    int idx = beg;
    for (; idx + 4 <= end; idx += 4) {
        int ss[4];
        float aa[4];
#pragma unroll
        for (int uu = 0; uu < 4; ++uu) ss[uu] = ssrc[idx + uu];
#pragma unroll
        for (int uu = 0; uu < 4; ++uu)
            aa[uu] = __expf(pe[(size_t)(idx + uu) * 8 + hl] - m_l) * si_l;
        bf16x2 p[4][2];
        __bf16 pt[4];
#pragma unroll
        for (int uu = 0; uu < 4; ++uu) {
            const __bf16* f = featb + (size_t)ss[uu] * HD;
            p[uu][0] = *(const bf16x2*)&f[2 * lane];
            p[uu][1] = *(const bf16x2*)&f[128 + 2 * lane];
            if (TAIL) pt[uu] = f[256 + lane];
        }
#pragma unroll
        for (int uu = 0; uu < 4; ++uu) {
            float w0 = __shfl(aa[uu], hg[0]);
            float w1 = __shfl(aa[uu], hg[1]);
            acc[0][0] += w0 * (float)p[uu][0].x;
            acc[0][1] += w0 * (float)p[uu][0].y;
            acc[1][0] += w1 * (float)p[uu][1].x;
            acc[1][1] += w1 * (float)p[uu][1].y;
            if (TAIL) {
                float wt = __shfl(aa[uu], ht);
                acct += wt * (float)pt[uu];
            }
        }
    }
    for (; idx < end; ++idx) {
        int s = ssrc[idx];
        float a = __expf(pe[(size_t)idx * 8 + hl] - m_l) * si_l;
        const __bf16* f = featb + (size_t)s * HD;
        float w0 = __shfl(a, hg[0]);
        float w1 = __shfl(a, hg[1]);
        bf16x2 p0 = *(const bf16x2*)&f[2 * lane];
        bf16x2 p1 = *(const bf16x2*)&f[128 + 2 * lane];
        acc[0][0] += w0 * (float)p0.x;
        acc[0][1] += w0 * (float)p0.y;
        acc[1][0] += w1 * (float)p1.x;
        acc[1][1] += w1 * (float)p1.y;
        if (TAIL) {
            float wt = __shfl(a, ht);
            acct += wt * (float)f[256 + lane];
        }
    }

    if (MODE == 0) {
        // ELU then split-bf16 write (feeds layer-2 GEMM via global_load_lds)
#pragma unroll
        for (int g = 0; g < 2; ++g) {
            float x0 = acc[g][0], x1 = acc[g][1];
            x0 = x0 > 0.f ? x0 : expm1f(x0);
            x1 = x1 > 0.f ? x1 : expm1f(x1);
            __bf16 h0 = (__bf16)x0, h1 = (__bf16)x1;
            bf16x2 vh = {h0, h1};
            bf16x2 vl = {(__bf16)(x0 - (float)h0), (__bf16)(x1 - (float)h1)};
            *(bf16x2*)&outh[(size_t)n * 256 + 128 * g + 2 * lane] = vh;
            *(bf16x2*)&outl[(size_t)n * 256 + 128 * g + 2 * lane] = vl;
        }
    } else {
#pragma unroll
        for (int g = 0; g < 2; ++g) {
            red[wid][128 * g + 2 * lane] = acc[g][0];
            red[wid][128 * g + 2 * lane + 1] = acc[g][1];
        }
        red[wid][256 + lane] = acct;
        if (lane < D) {
            float s = 0.f;
#pragma unroll
            for (int hh = 0; hh < 8; ++hh) s += red[wid][hh * D + lane];
            outf[(size_t)n * D + lane] = s * 0.125f;
        }
    }
}

// ---------------------------------------------------------------------------

extern "C" void kernel_launch(void* const* d_in, const int* in_sizes, int n_in,
                              void* d_out, int out_size, void* d_ws, size_t ws_size,
                              hipStream_t stream) {
    const float* features = (const float*)d_in[0];
    const int* src = (const int*)d_in[1];
    const int* dst = (const int*)d_in[2];
    const float* W1 = (const float*)d_in[3];
    const float* al1 = (const float*)d_in[4];
    const float* ar1 = (const float*)d_in[5];
    const float* W2 = (const float*)d_in[6];
    const float* al2 = (const float*)d_in[7];
    const float* ar2 = (const float*)d_in[8];

    const int N = in_sizes[0] / 512;  // 50000
    const int E = in_sizes[1];        // 800000

    char* ws = (char*)d_ws;
    size_t off = 0;
    auto alloc = [&](size_t bytes) -> void* {
        void* p = ws + off;
        off = (off + bytes + 255) & ~(size_t)255;
        return p;
    };
    __bf16* feat1b = (__bf16*)alloc((size_t)N * 256 * 2);
    __bf16* h_hi = (__bf16*)alloc((size_t)N * 256 * 2);
    __bf16* h_lo = (__bf16*)alloc((size_t)N * 256 * 2);
    __bf16* feat2b = (__bf16*)alloc((size_t)N * 320 * 2);
    float* pe = (float*)alloc((size_t)E * 8 * 4);
    float* el1 = (float*)alloc((size_t)N * 8 * 4);
    float* er1 = (float*)alloc((size_t)N * 8 * 4);
    float* el2 = (float*)alloc((size_t)N * 8 * 4);
    float* er2 = (float*)alloc((size_t)N * 8 * 4);
    int* cnt = (int*)alloc((size_t)N * 4);
    int* incl = (int*)alloc((size_t)N * 4);
    int* row_ptr = (int*)alloc((size_t)(N + 1) * 4);
    int* cursor = (int*)alloc((size_t)N * 4);
    int* bsum = (int*)alloc(256 * 4);
    int* boff = (int*)alloc(256 * 4);
    int* ssrc = (int*)alloc((size_t)E * 4);
    int* sdst = (int*)alloc((size_t)E * 4);
    __bf16* Wt1h = (__bf16*)alloc((size_t)512 * 256 * 2);
    __bf16* Wt1l = (__bf16*)alloc((size_t)512 * 256 * 2);
    __bf16* Wt2h = (__bf16*)alloc((size_t)256 * 320 * 2);
    __bf16* Wt2l = (__bf16*)alloc((size_t)256 * 320 * 2);

    const int NB = (N + 255) / 256;

    // ---- CSR build ----
    hipMemsetAsync(cnt, 0, (size_t)N * 4, stream);
    hist_kernel<<<(E + 255) / 256, 256, 0, stream>>>(dst, cnt, E);
    scan_blk<<<NB, 256, 0, stream>>>(cnt, incl, bsum, N);
    scan_top<<<1, 256, 0, stream>>>(bsum, boff, NB);
    scan_fix<<<NB, 256, 0, stream>>>(incl, boff, cnt, row_ptr, cursor, N);
    fill_kernel<<<(E + 255) / 256, 256, 0, stream>>>(src, dst, cursor, ssrc, sdst, E);

    // ---- weight split/transpose ----
    split_w_kernel<<<(512 * 256 + 255) / 256, 256, 0, stream>>>(W1, Wt1h, Wt1l, 512, 256);
    split_w_kernel<<<(256 * 320 + 255) / 256, 256, 0, stream>>>(W2, Wt2h, Wt2l, 256, 320);

    const int mblk = (N + 63) / 64;

    // ---- layer 1 ----
    gemm_fused<256, 4, true><<<mblk, 256, 0, stream>>>(
        features, nullptr, nullptr, Wt1h, Wt1l, al1, ar1, feat1b, el1, er1, N, 512);
    edge_score_kernel<<<(E + 255) / 256, 256, 0, stream>>>(ssrc, sdst, el1, er1, pe, E);
    gat_aggregate<32, 0><<<(N + 3) / 4, 256, 0, stream>>>(
        feat1b, pe, row_ptr, ssrc, h_hi, h_lo, nullptr, N);

    // ---- layer 2 ----
    gemm_fused<320, 5, false><<<mblk, 256, 0, stream>>>(
        nullptr, h_hi, h_lo, Wt2h, Wt2l, al2, ar2, feat2b, el2, er2, N, 256);
    edge_score_kernel<<<(E + 255) / 256, 256, 0, stream>>>(ssrc, sdst, el2, er2, pe, E);
    gat_aggregate<40, 1><<<(N + 3) / 4, 256, 0, stream>>>(
        feat2b, pe, row_ptr, ssrc, nullptr, nullptr, (float*)d_out, N);
}

// Round 6
// 377.474 us; speedup vs baseline: 1.0932x; 1.0932x over previous
//
#include <hip/hip_runtime.h>
#include <math.h>

typedef float f32x4 __attribute__((ext_vector_type(4)));
typedef __bf16 bf16x2 __attribute__((ext_vector_type(2)));
typedef __bf16 bf16x4 __attribute__((ext_vector_type(4)));
typedef __bf16 bf16x8 __attribute__((ext_vector_type(8)));

// ---------------------------------------------------------------------------
// GAT 2-layer forward.
// GEMMs: split-bf16 MFMA (hi/lo, 3 terms). BM=32, 2 waves/block, wave strip =
// 32 x 128/160 (= exactly 4 heads). A in LDS padded to 40 bf16/row (bank-
// conflict-free frag reads), double-buffered, 1 barrier/K-step. B pre-packed
// fragment-major: each wave B-frag load = one coalesced 1KB L2-resident read,
// zero LDS. Fused el/er epilogue via per-wave ctile.
// Aggregation: CSR by dst; streaming pe[E][8]; 4x-unrolled bf16 gather.
// ---------------------------------------------------------------------------

__global__ void hist_kernel(const int* __restrict__ dst, int* __restrict__ cnt, int E) {
    int e = blockIdx.x * blockDim.x + threadIdx.x;
    if (e < E) atomicAdd(&cnt[dst[e]], 1);
}

__global__ __launch_bounds__(256) void scan_blk(const int* __restrict__ cnt,
                                                int* __restrict__ incl,
                                                int* __restrict__ bsum, int n) {
    __shared__ int sd[256];
    const int t = threadIdx.x;
    int i = blockIdx.x * 256 + t;
    int v = (i < n) ? cnt[i] : 0;
    sd[t] = v;
    __syncthreads();
#pragma unroll
    for (int off = 1; off < 256; off <<= 1) {
        int x = (t >= off) ? sd[t - off] : 0;
        __syncthreads();
        sd[t] += x;
        __syncthreads();
    }
    if (i < n) incl[i] = sd[t];
    if (t == 255) bsum[blockIdx.x] = sd[255];
}

__global__ __launch_bounds__(256) void scan_top(const int* __restrict__ bsum,
                                                int* __restrict__ boff, int nb) {
    __shared__ int sd[256];
    const int t = threadIdx.x;
    int v = (t < nb) ? bsum[t] : 0;
    sd[t] = v;
    __syncthreads();
#pragma unroll
    for (int off = 1; off < 256; off <<= 1) {
        int x = (t >= off) ? sd[t - off] : 0;
        __syncthreads();
        sd[t] += x;
        __syncthreads();
    }
    if (t < nb) boff[t] = sd[t] - v;
}

__global__ void scan_fix(const int* __restrict__ incl, const int* __restrict__ boff,
                         const int* __restrict__ cnt, int* __restrict__ row_ptr,
                         int* __restrict__ cursor, int n) {
    int i = blockIdx.x * blockDim.x + threadIdx.x;
    if (i >= n) return;
    int total = incl[i] + boff[i >> 8];
    row_ptr[i + 1] = total;
    cursor[i] = total - cnt[i];
    if (i == 0) row_ptr[0] = 0;
}

__global__ void fill_kernel(const int* __restrict__ src, const int* __restrict__ dst,
                            int* __restrict__ cursor, int* __restrict__ ssrc,
                            int* __restrict__ sdst, int E) {
    int e = blockIdx.x * blockDim.x + threadIdx.x;
    if (e < E) {
        int d = dst[e];
        int pos = atomicAdd(&cursor[d], 1);
        ssrc[pos] = src[e];
        sdst[pos] = d;
    }
}

// ---------------------------------------------------------------------------
// Pack W[K][N] fp32 into fragment-major split-bf16 chunks.
// chunk c = (k0/32)*(N/16) + colgroup; within chunk: lane l, elem e holds
// B[k0 + (l>>4)*8 + e][colgroup*16 + (l&15)]  (exactly the MFMA B-frag order,
// so a wave's frag load = Bp[c*512 + lane*8 .. +7], one coalesced 1KB read).
// ---------------------------------------------------------------------------
__global__ void pack_b_kernel(const float* __restrict__ W, __bf16* __restrict__ Bh,
                              __bf16* __restrict__ Bl, int K, int N) {
    int idx = blockIdx.x * blockDim.x + threadIdx.x;
    if (idx >= K * N) return;
    int e = idx & 7;
    int l = (idx >> 3) & 63;
    int c = idx >> 9;
    int ng = N >> 4;
    int g = c % ng;
    int k0 = (c / ng) << 5;
    int col = g * 16 + (l & 15);
    int k = k0 + ((l >> 4) << 3) + e;
    float x = W[(size_t)k * N + col];
    __bf16 h = (__bf16)x;
    Bh[idx] = h;
    Bl[idx] = (__bf16)(x - (float)h);
}

// ---------------------------------------------------------------------------
// Split-bf16 MFMA GEMM + fused el/er epilogue.
// FP32A=true : A fp32, reg-staged with in-flight hi/lo split (layer 1).
// FP32A=false: A pre-split bf16 (Ahg/Alg) from agg1 (layer 2).
// ---------------------------------------------------------------------------
template <int BN, int NREP, bool FP32A>
__global__ __launch_bounds__(128) void gemm_fused(
    const float* __restrict__ Af, const __bf16* __restrict__ Ahg,
    const __bf16* __restrict__ Alg, const __bf16* __restrict__ Bph,
    const __bf16* __restrict__ Bpl, const float* __restrict__ al,
    const float* __restrict__ ar, __bf16* __restrict__ featb,
    float* __restrict__ el, float* __restrict__ er, int M, int K) {
    constexpr int WN = NREP * 16;  // per-wave strip; BN == 2*WN
    constexpr int D = BN / 8;      // head dim; WN == 4*D (strip = 4 heads)

    __shared__ __align__(16) __bf16 Ah[2][32][40];  // +8 pad: 80B stride,
    __shared__ __align__(16) __bf16 Al[2][32][40];  // conflict-free frag reads
    __shared__ __align__(16) float ctile[2][16][WN + 1];

    const int t = threadIdx.x;
    const int lane = t & 63;
    const int wid = t >> 6;
    const int row0 = blockIdx.x * 32;
    const int colw = wid * WN;
    const int fr = lane & 15;
    const int kq = lane >> 4;
    const int kg = kq * 8;
    const int sr = t >> 2;          // staging row 0..31
    const int sc = (t & 3) * 8;     // staging col {0,8,16,24}

    // staged-A registers (software pipeline depth 1)
    float4 av0, av1;
    bf16x8 avh, avl;

    auto loadA = [&](int k0) {
        int gr = row0 + sr;
        if (gr >= M) gr = M - 1;
        if constexpr (FP32A) {
            av0 = *(const float4*)&Af[(size_t)gr * K + k0 + sc];
            av1 = *(const float4*)&Af[(size_t)gr * K + k0 + sc + 4];
        } else {
            avh = *(const bf16x8*)&Ahg[(size_t)gr * K + k0 + sc];
            avl = *(const bf16x8*)&Alg[(size_t)gr * K + k0 + sc];
        }
    };
    auto storeA = [&](int p) {
        if constexpr (FP32A) {
            __bf16 h0 = (__bf16)av0.x, h1 = (__bf16)av0.y, h2 = (__bf16)av0.z,
                   h3 = (__bf16)av0.w;
            __bf16 h4 = (__bf16)av1.x, h5 = (__bf16)av1.y, h6 = (__bf16)av1.z,
                   h7 = (__bf16)av1.w;
            bf16x8 hv = {h0, h1, h2, h3, h4, h5, h6, h7};
            bf16x8 lv = {(__bf16)(av0.x - (float)h0), (__bf16)(av0.y - (float)h1),
                         (__bf16)(av0.z - (float)h2), (__bf16)(av0.w - (float)h3),
                         (__bf16)(av1.x - (float)h4), (__bf16)(av1.y - (float)h5),
                         (__bf16)(av1.z - (float)h6), (__bf16)(av1.w - (float)h7)};
            *(bf16x8*)&Ah[p][sr][sc] = hv;
            *(bf16x8*)&Al[p][sr][sc] = lv;
        } else {
            *(bf16x8*)&Ah[p][sr][sc] = avh;
            *(bf16x8*)&Al[p][sr][sc] = avl;
        }
    };

    f32x4 acc[2][NREP] = {};

    loadA(0);
    int p = 0;
    for (int k0 = 0; k0 < K; k0 += 32) {
        storeA(p);                      // stage current K-slab (ds_write_b128)
        if (k0 + 32 < K) loadA(k0 + 32);  // prefetch next slab into regs
        // B frags: coalesced 1KB chunk loads, L2-resident, issued pre-barrier
        bf16x8 bh[NREP], bl[NREP];
        const int c0 = (k0 >> 5) * (BN >> 4) + (colw >> 4);
#pragma unroll
        for (int n = 0; n < NREP; ++n) {
            size_t o = (size_t)(c0 + n) * 512 + lane * 8;
            bh[n] = *(const bf16x8*)&Bph[o];
            bl[n] = *(const bf16x8*)&Bpl[o];
        }
        __syncthreads();                // A(p) visible to both waves
        bf16x8 ah0 = *(const bf16x8*)&Ah[p][fr][kg];
        bf16x8 ah1 = *(const bf16x8*)&Ah[p][fr + 16][kg];
        bf16x8 al0 = *(const bf16x8*)&Al[p][fr][kg];
        bf16x8 al1 = *(const bf16x8*)&Al[p][fr + 16][kg];
#pragma unroll
        for (int n = 0; n < NREP; ++n) {
            acc[0][n] = __builtin_amdgcn_mfma_f32_16x16x32_bf16(ah0, bh[n], acc[0][n], 0, 0, 0);
            acc[0][n] = __builtin_amdgcn_mfma_f32_16x16x32_bf16(al0, bh[n], acc[0][n], 0, 0, 0);
            acc[0][n] = __builtin_amdgcn_mfma_f32_16x16x32_bf16(ah0, bl[n], acc[0][n], 0, 0, 0);
            acc[1][n] = __builtin_amdgcn_mfma_f32_16x16x32_bf16(ah1, bh[n], acc[1][n], 0, 0, 0);
            acc[1][n] = __builtin_amdgcn_mfma_f32_16x16x32_bf16(al1, bh[n], acc[1][n], 0, 0, 0);
            acc[1][n] = __builtin_amdgcn_mfma_f32_16x16x32_bf16(ah1, bl[n], acc[1][n], 0, 0, 0);
        }
        p ^= 1;
    }

    // ---- epilogue 1: bf16 feat stores ----
#pragma unroll
    for (int m = 0; m < 2; ++m) {
        int rbase = row0 + m * 16 + kq * 4;
#pragma unroll
        for (int n = 0; n < NREP; ++n) {
            int col = colw + n * 16 + fr;
#pragma unroll
            for (int i = 0; i < 4; ++i) {
                int r = rbase + i;
                if (r < M) featb[(size_t)r * BN + col] = (__bf16)acc[m][n][i];
            }
        }
    }

    // ---- epilogue 2: el/er (wave strip == heads wid*4 .. wid*4+3) ----
#pragma unroll
    for (int m = 0; m < 2; ++m) {
#pragma unroll
        for (int n = 0; n < NREP; ++n)
#pragma unroll
            for (int i = 0; i < 4; ++i)
                ctile[wid][kq * 4 + i][n * 16 + fr] = acc[m][n][i];
        // same-wave LDS RAW: compiler orders via lgkmcnt
        int r = lane & 15;
        int hh = lane >> 4;
        int h = wid * 4 + hh;
        float sl = 0.f, sr_ = 0.f;
#pragma unroll 8
        for (int d = 0; d < D; ++d) {
            float v = ctile[wid][r][hh * D + d];
            sl += v * al[h * D + d];
            sr_ += v * ar[h * D + d];
        }
        int gr = row0 + m * 16 + r;
        if (gr < M) {
            el[(size_t)gr * 8 + h] = sl;
            er[(size_t)gr * 8 + h] = sr_;
        }
        __syncthreads();  // ctile reuse between m-halves (cheap, 2 iters)
    }
}

__device__ __forceinline__ float leaky02(float x) { return x > 0.f ? x : 0.2f * x; }

// edge-parallel raw scores (CSR order): pe[pos][8] = leaky(el[s]+er[d])
__global__ void edge_score_kernel(const int* __restrict__ ssrc, const int* __restrict__ sdst,
                                  const float* __restrict__ el, const float* __restrict__ er,
                                  float* __restrict__ pe, int E) {
    int pos = blockIdx.x * blockDim.x + threadIdx.x;
    if (pos >= E) return;
    int s = ssrc[pos], d = sdst[pos];
    float4 l0 = *(const float4*)&el[(size_t)s * 8];
    float4 l1 = *(const float4*)&el[(size_t)s * 8 + 4];
    float4 r0 = *(const float4*)&er[(size_t)d * 8];
    float4 r1 = *(const float4*)&er[(size_t)d * 8 + 4];
    float4 o0 = {leaky02(l0.x + r0.x), leaky02(l0.y + r0.y),
                 leaky02(l0.z + r0.z), leaky02(l0.w + r0.w)};
    float4 o1 = {leaky02(l1.x + r1.x), leaky02(l1.y + r1.y),
                 leaky02(l1.z + r1.z), leaky02(l1.w + r1.w)};
    *(float4*)&pe[(size_t)pos * 8] = o0;
    *(float4*)&pe[(size_t)pos * 8 + 4] = o1;
}

// ---------------------------------------------------------------------------
// Edge-softmax aggregation, one wave per dst node. H=8. Phase-B 4x unrolled.
// MODE 0 (D=32): outh/outl = split-bf16 ELU(sum)  (feeds layer-2 GEMM A)
// MODE 1 (D=40): outf[n,40] = head-mean (final output)
// ---------------------------------------------------------------------------
template <int D, int MODE>
__global__ __launch_bounds__(256) void gat_aggregate(
    const __bf16* __restrict__ featb, const float* __restrict__ pe,
    const int* __restrict__ row_ptr, const int* __restrict__ ssrc,
    __bf16* __restrict__ outh, __bf16* __restrict__ outl,
    float* __restrict__ outf, int N) {
    constexpr int HD = 8 * D;
    constexpr int TAIL = HD - 256;
    __shared__ float red[4][MODE ? HD : 1];

    const int wid = threadIdx.x >> 6;
    const int lane = threadIdx.x & 63;
    const int n = blockIdx.x * 4 + wid;
    if (n >= N) return;

    const int beg = row_ptr[n];
    const int end = row_ptr[n + 1];
    const int hl = lane & 7;
    const int sl = lane >> 3;

    float m_l = -INFINITY;
    for (int idx = beg + sl; idx < end; idx += 8)
        m_l = fmaxf(m_l, pe[(size_t)idx * 8 + hl]);
    m_l = fmaxf(m_l, __shfl_xor(m_l, 8));
    m_l = fmaxf(m_l, __shfl_xor(m_l, 16));
    m_l = fmaxf(m_l, __shfl_xor(m_l, 32));
    float s_l = 0.f;
    for (int idx = beg + sl; idx < end; idx += 8)
        s_l += __expf(pe[(size_t)idx * 8 + hl] - m_l);
    s_l += __shfl_xor(s_l, 8);
    s_l += __shfl_xor(s_l, 16);
    s_l += __shfl_xor(s_l, 32);
    const float si_l = 1.0f / (s_l + 1e-9f);

    int hg[2], ht = 0;
#pragma unroll
    for (int g = 0; g < 2; ++g) hg[g] = (128 * g + 2 * lane) / D;
    if (TAIL) ht = (256 + lane) / D;

    float acc[2][2] = {};
    float acct = 0.f;
    int idx = beg;
    for (; idx + 4 <= end; idx += 4) {
        int ss[4];
        float aa[4];
#pragma unroll
        for (int uu = 0; uu < 4; ++uu) ss[uu] = ssrc[idx + uu];
#pragma unroll
        for (int uu = 0; uu < 4; ++uu)
            aa[uu] = __expf(pe[(size_t)(idx + uu) * 8 + hl] - m_l) * si_l;
        bf16x2 p[4][2];
        __bf16 pt[4];
#pragma unroll
        for (int uu = 0; uu < 4; ++uu) {
            const __bf16* f = featb + (size_t)ss[uu] * HD;
            p[uu][0] = *(const bf16x2*)&f[2 * lane];
            p[uu][1] = *(const bf16x2*)&f[128 + 2 * lane];
            if (TAIL) pt[uu] = f[256 + lane];
        }
#pragma unroll
        for (int uu = 0; uu < 4; ++uu) {
            float w0 = __shfl(aa[uu], hg[0]);
            float w1 = __shfl(aa[uu], hg[1]);
            acc[0][0] += w0 * (float)p[uu][0].x;
            acc[0][1] += w0 * (float)p[uu][0].y;
            acc[1][0] += w1 * (float)p[uu][1].x;
            acc[1][1] += w1 * (float)p[uu][1].y;
            if (TAIL) {
                float wt = __shfl(aa[uu], ht);
                acct += wt * (float)pt[uu];
            }
        }
    }
    for (; idx < end; ++idx) {
        int s = ssrc[idx];
        float a = __expf(pe[(size_t)idx * 8 + hl] - m_l) * si_l;
        const __bf16* f = featb + (size_t)s * HD;
        float w0 = __shfl(a, hg[0]);
        float w1 = __shfl(a, hg[1]);
        bf16x2 p0 = *(const bf16x2*)&f[2 * lane];
        bf16x2 p1 = *(const bf16x2*)&f[128 + 2 * lane];
        acc[0][0] += w0 * (float)p0.x;
        acc[0][1] += w0 * (float)p0.y;
        acc[1][0] += w1 * (float)p1.x;
        acc[1][1] += w1 * (float)p1.y;
        if (TAIL) {
            float wt = __shfl(a, ht);
            acct += wt * (float)f[256 + lane];
        }
    }

    if (MODE == 0) {
#pragma unroll
        for (int g = 0; g < 2; ++g) {
            float x0 = acc[g][0], x1 = acc[g][1];
            x0 = x0 > 0.f ? x0 : expm1f(x0);
            x1 = x1 > 0.f ? x1 : expm1f(x1);
            __bf16 h0 = (__bf16)x0, h1 = (__bf16)x1;
            bf16x2 vh = {h0, h1};
            bf16x2 vl = {(__bf16)(x0 - (float)h0), (__bf16)(x1 - (float)h1)};
            *(bf16x2*)&outh[(size_t)n * 256 + 128 * g + 2 * lane] = vh;
            *(bf16x2*)&outl[(size_t)n * 256 + 128 * g + 2 * lane] = vl;
        }
    } else {
#pragma unroll
        for (int g = 0; g < 2; ++g) {
            red[wid][128 * g + 2 * lane] = acc[g][0];
            red[wid][128 * g + 2 * lane + 1] = acc[g][1];
        }
        red[wid][256 + lane] = acct;
        if (lane < D) {
            float s = 0.f;
#pragma unroll
            for (int hh = 0; hh < 8; ++hh) s += red[wid][hh * D + lane];
            outf[(size_t)n * D + lane] = s * 0.125f;
        }
    }
}

// ---------------------------------------------------------------------------

extern "C" void kernel_launch(void* const* d_in, const int* in_sizes, int n_in,
                              void* d_out, int out_size, void* d_ws, size_t ws_size,
                              hipStream_t stream) {
    const float* features = (const float*)d_in[0];
    const int* src = (const int*)d_in[1];
    const int* dst = (const int*)d_in[2];
    const float* W1 = (const float*)d_in[3];
    const float* al1 = (const float*)d_in[4];
    const float* ar1 = (const float*)d_in[5];
    const float* W2 = (const float*)d_in[6];
    const float* al2 = (const float*)d_in[7];
    const float* ar2 = (const float*)d_in[8];

    const int N = in_sizes[0] / 512;  // 50000
    const int E = in_sizes[1];        // 800000

    char* ws = (char*)d_ws;
    size_t off = 0;
    auto alloc = [&](size_t bytes) -> void* {
        void* p = ws + off;
        off = (off + bytes + 255) & ~(size_t)255;
        return p;
    };
    __bf16* feat1b = (__bf16*)alloc((size_t)N * 256 * 2);
    __bf16* h_hi = (__bf16*)alloc((size_t)N * 256 * 2);
    __bf16* h_lo = (__bf16*)alloc((size_t)N * 256 * 2);
    __bf16* feat2b = (__bf16*)alloc((size_t)N * 320 * 2);
    float* pe = (float*)alloc((size_t)E * 8 * 4);
    float* el1 = (float*)alloc((size_t)N * 8 * 4);
    float* er1 = (float*)alloc((size_t)N * 8 * 4);
    float* el2 = (float*)alloc((size_t)N * 8 * 4);
    float* er2 = (float*)alloc((size_t)N * 8 * 4);
    int* cnt = (int*)alloc((size_t)N * 4);
    int* incl = (int*)alloc((size_t)N * 4);
    int* row_ptr = (int*)alloc((size_t)(N + 1) * 4);
    int* cursor = (int*)alloc((size_t)N * 4);
    int* bsum = (int*)alloc(256 * 4);
    int* boff = (int*)alloc(256 * 4);
    int* ssrc = (int*)alloc((size_t)E * 4);
    int* sdst = (int*)alloc((size_t)E * 4);
    __bf16* Bp1h = (__bf16*)alloc((size_t)512 * 256 * 2);
    __bf16* Bp1l = (__bf16*)alloc((size_t)512 * 256 * 2);
    __bf16* Bp2h = (__bf16*)alloc((size_t)256 * 320 * 2);
    __bf16* Bp2l = (__bf16*)alloc((size_t)256 * 320 * 2);

    const int NB = (N + 255) / 256;

    // ---- CSR build ----
    hipMemsetAsync(cnt, 0, (size_t)N * 4, stream);
    hist_kernel<<<(E + 255) / 256, 256, 0, stream>>>(dst, cnt, E);
    scan_blk<<<NB, 256, 0, stream>>>(cnt, incl, bsum, N);
    scan_top<<<1, 256, 0, stream>>>(bsum, boff, NB);
    scan_fix<<<NB, 256, 0, stream>>>(incl, boff, cnt, row_ptr, cursor, N);
    fill_kernel<<<(E + 255) / 256, 256, 0, stream>>>(src, dst, cursor, ssrc, sdst, E);

    // ---- weight split + fragment-major pack ----
    pack_b_kernel<<<(512 * 256 + 255) / 256, 256, 0, stream>>>(W1, Bp1h, Bp1l, 512, 256);
    pack_b_kernel<<<(256 * 320 + 255) / 256, 256, 0, stream>>>(W2, Bp2h, Bp2l, 256, 320);

    const int mblk = (N + 31) / 32;  // 1563

    // ---- layer 1 ----
    gemm_fused<256, 8, true><<<mblk, 128, 0, stream>>>(
        features, nullptr, nullptr, Bp1h, Bp1l, al1, ar1, feat1b, el1, er1, N, 512);
    edge_score_kernel<<<(E + 255) / 256, 256, 0, stream>>>(ssrc, sdst, el1, er1, pe, E);
    gat_aggregate<32, 0><<<(N + 3) / 4, 256, 0, stream>>>(
        feat1b, pe, row_ptr, ssrc, h_hi, h_lo, nullptr, N);

    // ---- layer 2 ----
    gemm_fused<320, 10, false><<<mblk, 128, 0, stream>>>(
        nullptr, h_hi, h_lo, Bp2h, Bp2l, al2, ar2, feat2b, el2, er2, N, 256);
    edge_score_kernel<<<(E + 255) / 256, 256, 0, stream>>>(ssrc, sdst, el2, er2, pe, E);
    gat_aggregate<40, 1><<<(N + 3) / 4, 256, 0, stream>>>(
        feat2b, pe, row_ptr, ssrc, nullptr, nullptr, (float*)d_out, N);
}

// Round 7
// 370.905 us; speedup vs baseline: 1.1126x; 1.0177x over previous
//
#include <hip/hip_runtime.h>
#include <math.h>

typedef float f32x4 __attribute__((ext_vector_type(4)));
typedef __bf16 bf16x2 __attribute__((ext_vector_type(2)));
typedef __bf16 bf16x4 __attribute__((ext_vector_type(4)));
typedef __bf16 bf16x8 __attribute__((ext_vector_type(8)));

// ---------------------------------------------------------------------------
// GAT 2-layer forward.
// GEMMs: split-bf16 MFMA (hi/lo, 3 terms). BM=32, 4 waves (256 thr), wave
// strip = 32 x 64/80 (= exactly 2 heads). A staged in LDS in FRAGMENT-MAJOR
// order with XOR swizzle (x ^= x>>3): both ds_write (staging) and ds_read
// (frag fetch) cover all 8 bank-spans per 8-lane group => conflict-free by
// construction. B pre-packed fragment-major, direct L2->reg chunk loads.
// Fused el/er epilogue on per-wave ctile (no cross-wave barriers).
// Aggregation: CSR by dst; streaming pe[E][8]; 4x-unrolled bf16 gather.
// ---------------------------------------------------------------------------

__global__ void hist_kernel(const int* __restrict__ dst, int* __restrict__ cnt, int E) {
    int e = blockIdx.x * blockDim.x + threadIdx.x;
    if (e < E) atomicAdd(&cnt[dst[e]], 1);
}

__global__ __launch_bounds__(256) void scan_blk(const int* __restrict__ cnt,
                                                int* __restrict__ incl,
                                                int* __restrict__ bsum, int n) {
    __shared__ int sd[256];
    const int t = threadIdx.x;
    int i = blockIdx.x * 256 + t;
    int v = (i < n) ? cnt[i] : 0;
    sd[t] = v;
    __syncthreads();
#pragma unroll
    for (int off = 1; off < 256; off <<= 1) {
        int x = (t >= off) ? sd[t - off] : 0;
        __syncthreads();
        sd[t] += x;
        __syncthreads();
    }
    if (i < n) incl[i] = sd[t];
    if (t == 255) bsum[blockIdx.x] = sd[255];
}

__global__ __launch_bounds__(256) void scan_top(const int* __restrict__ bsum,
                                                int* __restrict__ boff, int nb) {
    __shared__ int sd[256];
    const int t = threadIdx.x;
    int v = (t < nb) ? bsum[t] : 0;
    sd[t] = v;
    __syncthreads();
#pragma unroll
    for (int off = 1; off < 256; off <<= 1) {
        int x = (t >= off) ? sd[t - off] : 0;
        __syncthreads();
        sd[t] += x;
        __syncthreads();
    }
    if (t < nb) boff[t] = sd[t] - v;
}

__global__ void scan_fix(const int* __restrict__ incl, const int* __restrict__ boff,
                         const int* __restrict__ cnt, int* __restrict__ row_ptr,
                         int* __restrict__ cursor, int n) {
    int i = blockIdx.x * blockDim.x + threadIdx.x;
    if (i >= n) return;
    int total = incl[i] + boff[i >> 8];
    row_ptr[i + 1] = total;
    cursor[i] = total - cnt[i];
    if (i == 0) row_ptr[0] = 0;
}

__global__ void fill_kernel(const int* __restrict__ src, const int* __restrict__ dst,
                            int* __restrict__ cursor, int* __restrict__ ssrc,
                            int* __restrict__ sdst, int E) {
    int e = blockIdx.x * blockDim.x + threadIdx.x;
    if (e < E) {
        int d = dst[e];
        int pos = atomicAdd(&cursor[d], 1);
        ssrc[pos] = src[e];
        sdst[pos] = d;
    }
}

// Pack W[K][N] fp32 into fragment-major split-bf16 1KB chunks (see R6).
__global__ void pack_b_kernel(const float* __restrict__ W, __bf16* __restrict__ Bh,
                              __bf16* __restrict__ Bl, int K, int N) {
    int idx = blockIdx.x * blockDim.x + threadIdx.x;
    if (idx >= K * N) return;
    int e = idx & 7;
    int l = (idx >> 3) & 63;
    int c = idx >> 9;
    int ng = N >> 4;
    int g = c % ng;
    int k0 = (c / ng) << 5;
    int col = g * 16 + (l & 15);
    int k = k0 + ((l >> 4) << 3) + e;
    float x = W[(size_t)k * N + col];
    __bf16 h = (__bf16)x;
    Bh[idx] = h;
    Bl[idx] = (__bf16)(x - (float)h);
}

__device__ __forceinline__ int swz6(int x) { return x ^ (x >> 3); }  // [0,64)->[0,64)

// ---------------------------------------------------------------------------
// Split-bf16 MFMA GEMM + fused el/er epilogue. BM=32, 256 threads, 4 waves.
// FP32A=true : A fp32, reg-staged with in-flight hi/lo split (layer 1).
// FP32A=false: A pre-split bf16 (Ahg/Alg) from agg1 (layer 2).
// ---------------------------------------------------------------------------
template <int BN, int NREP, bool FP32A>
__global__ __launch_bounds__(256, 4) void gemm_fused(
    const float* __restrict__ Af, const __bf16* __restrict__ Ahg,
    const __bf16* __restrict__ Alg, const __bf16* __restrict__ Bph,
    const __bf16* __restrict__ Bpl, const float* __restrict__ al,
    const float* __restrict__ ar, __bf16* __restrict__ featb,
    float* __restrict__ el, float* __restrict__ er, int M, int K) {
    constexpr int WN = NREP * 16;  // per-wave strip; BN == 4*WN
    constexpr int D = BN / 8;      // head dim; WN == 2*D (strip = 2 heads)

    struct StageT {
        __bf16 Ah[2][2][64][8];  // [dbuf][m-frag][swizzled slot][elem]  4KB
        __bf16 Al[2][2][64][8];  //                                     4KB
    };
    union Smem {
        StageT s;
        float ctile[4][16][WN + 1];  // per-wave epilogue scratch
    };
    __shared__ __align__(16) Smem u;

    const int t = threadIdx.x;
    const int lane = t & 63;
    const int wid = t >> 6;
    const int row0 = blockIdx.x * 32;
    const int colw = wid * WN;
    const int fr = lane & 15;
    const int kq = lane >> 4;
    // staging indices: 256 threads cover 32 rows x 32 cols, 4 elems/thread
    const int sr = t >> 3;          // row 0..31
    const int kc = (t & 7) * 4;     // col {0,4,...,28}
    const int m_s = sr >> 4;
    const int xs = (sr & 15) + 16 * (kc >> 3);  // fragment slot
    const int e0 = kc & 7;                      // 0 or 4

    // staged-A registers (pipeline depth 1)
    float4 av;
    bf16x4 avh, avl;

    auto loadA = [&](int k0) {
        int gr = row0 + sr;
        if (gr >= M) gr = M - 1;
        if constexpr (FP32A) {
            av = *(const float4*)&Af[(size_t)gr * K + k0 + kc];
        } else {
            avh = *(const bf16x4*)&Ahg[(size_t)gr * K + k0 + kc];
            avl = *(const bf16x4*)&Alg[(size_t)gr * K + k0 + kc];
        }
    };
    auto storeA = [&](int p) {
        if constexpr (FP32A) {
            __bf16 h0 = (__bf16)av.x, h1 = (__bf16)av.y, h2 = (__bf16)av.z,
                   h3 = (__bf16)av.w;
            bf16x4 hv = {h0, h1, h2, h3};
            bf16x4 lv = {(__bf16)(av.x - (float)h0), (__bf16)(av.y - (float)h1),
                         (__bf16)(av.z - (float)h2), (__bf16)(av.w - (float)h3)};
            *(bf16x4*)&u.s.Ah[p][m_s][swz6(xs)][e0] = hv;
            *(bf16x4*)&u.s.Al[p][m_s][swz6(xs)][e0] = lv;
        } else {
            *(bf16x4*)&u.s.Ah[p][m_s][swz6(xs)][e0] = avh;
            *(bf16x4*)&u.s.Al[p][m_s][swz6(xs)][e0] = avl;
        }
    };

    f32x4 acc[2][NREP] = {};

    loadA(0);
    int p = 0;
    for (int k0 = 0; k0 < K; k0 += 32) {
        // B frags first: coalesced 1KB chunk loads, L2-resident, max MLP
        bf16x8 bh[NREP], bl[NREP];
        const int c0 = (k0 >> 5) * (BN >> 4) + wid * NREP;
#pragma unroll
        for (int n = 0; n < NREP; ++n) {
            size_t o = (size_t)(c0 + n) * 512 + lane * 8;
            bh[n] = *(const bf16x8*)&Bph[o];
            bl[n] = *(const bf16x8*)&Bpl[o];
        }
        storeA(p);                        // stage current K-slab
        if (k0 + 32 < K) loadA(k0 + 32);  // prefetch next slab into regs
        __syncthreads();                  // A(p) visible to all waves
        const int sl_ = swz6(lane);
        bf16x8 ah0 = *(const bf16x8*)&u.s.Ah[p][0][sl_][0];
        bf16x8 ah1 = *(const bf16x8*)&u.s.Ah[p][1][sl_][0];
        bf16x8 al0 = *(const bf16x8*)&u.s.Al[p][0][sl_][0];
        bf16x8 al1 = *(const bf16x8*)&u.s.Al[p][1][sl_][0];
#pragma unroll
        for (int n = 0; n < NREP; ++n) {
            acc[0][n] = __builtin_amdgcn_mfma_f32_16x16x32_bf16(ah0, bh[n], acc[0][n], 0, 0, 0);
            acc[0][n] = __builtin_amdgcn_mfma_f32_16x16x32_bf16(al0, bh[n], acc[0][n], 0, 0, 0);
            acc[0][n] = __builtin_amdgcn_mfma_f32_16x16x32_bf16(ah0, bl[n], acc[0][n], 0, 0, 0);
            acc[1][n] = __builtin_amdgcn_mfma_f32_16x16x32_bf16(ah1, bh[n], acc[1][n], 0, 0, 0);
            acc[1][n] = __builtin_amdgcn_mfma_f32_16x16x32_bf16(al1, bh[n], acc[1][n], 0, 0, 0);
            acc[1][n] = __builtin_amdgcn_mfma_f32_16x16x32_bf16(ah1, bl[n], acc[1][n], 0, 0, 0);
        }
        p ^= 1;
    }

    // ---- epilogue 1: bf16 feat stores (C/D: col=fr, row=kq*4+i) ----
#pragma unroll
    for (int m = 0; m < 2; ++m) {
        int rbase = row0 + m * 16 + kq * 4;
#pragma unroll
        for (int n = 0; n < NREP; ++n) {
            int col = colw + n * 16 + fr;
#pragma unroll
            for (int i = 0; i < 4; ++i) {
                int r = rbase + i;
                if (r < M) featb[(size_t)r * BN + col] = (__bf16)acc[m][n][i];
            }
        }
    }

    // ---- epilogue 2: el/er (wave strip == heads {wid*2, wid*2+1}) ----
    __syncthreads();  // staging buffers dead; ctile (union) safe
#pragma unroll
    for (int m = 0; m < 2; ++m) {
#pragma unroll
        for (int n = 0; n < NREP; ++n)
#pragma unroll
            for (int i = 0; i < 4; ++i)
                u.ctile[wid][kq * 4 + i][n * 16 + fr] = acc[m][n][i];
        // per-wave ctile: same-wave RAW ordered by lgkmcnt, no barrier
        if (lane < 32) {
            int r = lane & 15;
            int hh = lane >> 4;  // 0..1
            int h = wid * 2 + hh;
            float sl = 0.f, sr_ = 0.f;
#pragma unroll 8
            for (int d = 0; d < D; ++d) {
                float v = u.ctile[wid][r][hh * D + d];
                sl += v * al[h * D + d];
                sr_ += v * ar[h * D + d];
            }
            int gr = row0 + m * 16 + r;
            if (gr < M) {
                el[(size_t)gr * 8 + h] = sl;
                er[(size_t)gr * 8 + h] = sr_;
            }
        }
    }
}

__device__ __forceinline__ float leaky02(float x) { return x > 0.f ? x : 0.2f * x; }

// edge-parallel raw scores (CSR order): pe[pos][8] = leaky(el[s]+er[d])
__global__ void edge_score_kernel(const int* __restrict__ ssrc, const int* __restrict__ sdst,
                                  const float* __restrict__ el, const float* __restrict__ er,
                                  float* __restrict__ pe, int E) {
    int pos = blockIdx.x * blockDim.x + threadIdx.x;
    if (pos >= E) return;
    int s = ssrc[pos], d = sdst[pos];
    float4 l0 = *(const float4*)&el[(size_t)s * 8];
    float4 l1 = *(const float4*)&el[(size_t)s * 8 + 4];
    float4 r0 = *(const float4*)&er[(size_t)d * 8];
    float4 r1 = *(const float4*)&er[(size_t)d * 8 + 4];
    float4 o0 = {leaky02(l0.x + r0.x), leaky02(l0.y + r0.y),
                 leaky02(l0.z + r0.z), leaky02(l0.w + r0.w)};
    float4 o1 = {leaky02(l1.x + r1.x), leaky02(l1.y + r1.y),
                 leaky02(l1.z + r1.z), leaky02(l1.w + r1.w)};
    *(float4*)&pe[(size_t)pos * 8] = o0;
    *(float4*)&pe[(size_t)pos * 8 + 4] = o1;
}

// ---------------------------------------------------------------------------
// Edge-softmax aggregation, one wave per dst node. H=8. Phase-B 4x unrolled.
// MODE 0 (D=32): outh/outl = split-bf16 ELU(sum)  (feeds layer-2 GEMM A)
// MODE 1 (D=40): outf[n,40] = head-mean (final output)
// ---------------------------------------------------------------------------
template <int D, int MODE>
__global__ __launch_bounds__(256) void gat_aggregate(
    const __bf16* __restrict__ featb, const float* __restrict__ pe,
    const int* __restrict__ row_ptr, const int* __restrict__ ssrc,
    __bf16* __restrict__ outh, __bf16* __restrict__ outl,
    float* __restrict__ outf, int N) {
    constexpr int HD = 8 * D;
    constexpr int TAIL = HD - 256;
    __shared__ float red[4][MODE ? HD : 1];

    const int wid = threadIdx.x >> 6;
    const int lane = threadIdx.x & 63;
    const int n = blockIdx.x * 4 + wid;
    if (n >= N) return;

    const int beg = row_ptr[n];
    const int end = row_ptr[n + 1];
    const int hl = lane & 7;
    const int sl = lane >> 3;

    float m_l = -INFINITY;
    for (int idx = beg + sl; idx < end; idx += 8)
        m_l = fmaxf(m_l, pe[(size_t)idx * 8 + hl]);
    m_l = fmaxf(m_l, __shfl_xor(m_l, 8));
    m_l = fmaxf(m_l, __shfl_xor(m_l, 16));
    m_l = fmaxf(m_l, __shfl_xor(m_l, 32));
    float s_l = 0.f;
    for (int idx = beg + sl; idx < end; idx += 8)
        s_l += __expf(pe[(size_t)idx * 8 + hl] - m_l);
    s_l += __shfl_xor(s_l, 8);
    s_l += __shfl_xor(s_l, 16);
    s_l += __shfl_xor(s_l, 32);
    const float si_l = 1.0f / (s_l + 1e-9f);

    int hg[2], ht = 0;
#pragma unroll
    for (int g = 0; g < 2; ++g) hg[g] = (128 * g + 2 * lane) / D;
    if (TAIL) ht = (256 + lane) / D;

    float acc[2][2] = {};
    float acct = 0.f;
    int idx = beg;
    for (; idx + 4 <= end; idx += 4) {
        int ss[4];
        float aa[4];
#pragma unroll
        for (int uu = 0; uu < 4; ++uu) ss[uu] = ssrc[idx + uu];
#pragma unroll
        for (int uu = 0; uu < 4; ++uu)
            aa[uu] = __expf(pe[(size_t)(idx + uu) * 8 + hl] - m_l) * si_l;
        bf16x2 p[4][2];
        __bf16 pt[4];
#pragma unroll
        for (int uu = 0; uu < 4; ++uu) {
            const __bf16* f = featb + (size_t)ss[uu] * HD;
            p[uu][0] = *(const bf16x2*)&f[2 * lane];
            p[uu][1] = *(const bf16x2*)&f[128 + 2 * lane];
            if (TAIL) pt[uu] = f[256 + lane];
        }
#pragma unroll
        for (int uu = 0; uu < 4; ++uu) {
            float w0 = __shfl(aa[uu], hg[0]);
            float w1 = __shfl(aa[uu], hg[1]);
            acc[0][0] += w0 * (float)p[uu][0].x;
            acc[0][1] += w0 * (float)p[uu][0].y;
            acc[1][0] += w1 * (float)p[uu][1].x;
            acc[1][1] += w1 * (float)p[uu][1].y;
            if (TAIL) {
                float wt = __shfl(aa[uu], ht);
                acct += wt * (float)pt[uu];
            }
        }
    }
    for (; idx < end; ++idx) {
        int s = ssrc[idx];
        float a = __expf(pe[(size_t)idx * 8 + hl] - m_l) * si_l;
        const __bf16* f = featb + (size_t)s * HD;
        float w0 = __shfl(a, hg[0]);
        float w1 = __shfl(a, hg[1]);
        bf16x2 p0 = *(const bf16x2*)&f[2 * lane];
        bf16x2 p1 = *(const bf16x2*)&f[128 + 2 * lane];
        acc[0][0] += w0 * (float)p0.x;
        acc[0][1] += w0 * (float)p0.y;
        acc[1][0] += w1 * (float)p1.x;
        acc[1][1] += w1 * (float)p1.y;
        if (TAIL) {
            float wt = __shfl(a, ht);
            acct += wt * (float)f[256 + lane];
        }
    }

    if (MODE == 0) {
#pragma unroll
        for (int g = 0; g < 2; ++g) {
            float x0 = acc[g][0], x1 = acc[g][1];
            x0 = x0 > 0.f ? x0 : expm1f(x0);
            x1 = x1 > 0.f ? x1 : expm1f(x1);
            __bf16 h0 = (__bf16)x0, h1 = (__bf16)x1;
            bf16x2 vh = {h0, h1};
            bf16x2 vl = {(__bf16)(x0 - (float)h0), (__bf16)(x1 - (float)h1)};
            *(bf16x2*)&outh[(size_t)n * 256 + 128 * g + 2 * lane] = vh;
            *(bf16x2*)&outl[(size_t)n * 256 + 128 * g + 2 * lane] = vl;
        }
    } else {
#pragma unroll
        for (int g = 0; g < 2; ++g) {
            red[wid][128 * g + 2 * lane] = acc[g][0];
            red[wid][128 * g + 2 * lane + 1] = acc[g][1];
        }
        red[wid][256 + lane] = acct;
        if (lane < D) {
            float s = 0.f;
#pragma unroll
            for (int hh = 0; hh < 8; ++hh) s += red[wid][hh * D + lane];
            outf[(size_t)n * D + lane] = s * 0.125f;
        }
    }
}

// ---------------------------------------------------------------------------

extern "C" void kernel_launch(void* const* d_in, const int* in_sizes, int n_in,
                              void* d_out, int out_size, void* d_ws, size_t ws_size,
                              hipStream_t stream) {
    const float* features = (const float*)d_in[0];
    const int* src = (const int*)d_in[1];
    const int* dst = (const int*)d_in[2];
    const float* W1 = (const float*)d_in[3];
    const float* al1 = (const float*)d_in[4];
    const float* ar1 = (const float*)d_in[5];
    const float* W2 = (const float*)d_in[6];
    const float* al2 = (const float*)d_in[7];
    const float* ar2 = (const float*)d_in[8];

    const int N = in_sizes[0] / 512;  // 50000
    const int E = in_sizes[1];        // 800000

    char* ws = (char*)d_ws;
    size_t off = 0;
    auto alloc = [&](size_t bytes) -> void* {
        void* p = ws + off;
        off = (off + bytes + 255) & ~(size_t)255;
        return p;
    };
    __bf16* feat1b = (__bf16*)alloc((size_t)N * 256 * 2);
    __bf16* h_hi = (__bf16*)alloc((size_t)N * 256 * 2);
    __bf16* h_lo = (__bf16*)alloc((size_t)N * 256 * 2);
    __bf16* feat2b = (__bf16*)alloc((size_t)N * 320 * 2);
    float* pe = (float*)alloc((size_t)E * 8 * 4);
    float* el1 = (float*)alloc((size_t)N * 8 * 4);
    float* er1 = (float*)alloc((size_t)N * 8 * 4);
    float* el2 = (float*)alloc((size_t)N * 8 * 4);
    float* er2 = (float*)alloc((size_t)N * 8 * 4);
    int* cnt = (int*)alloc((size_t)N * 4);
    int* incl = (int*)alloc((size_t)N * 4);
    int* row_ptr = (int*)alloc((size_t)(N + 1) * 4);
    int* cursor = (int*)alloc((size_t)N * 4);
    int* bsum = (int*)alloc(256 * 4);
    int* boff = (int*)alloc(256 * 4);
    int* ssrc = (int*)alloc((size_t)E * 4);
    int* sdst = (int*)alloc((size_t)E * 4);
    __bf16* Bp1h = (__bf16*)alloc((size_t)512 * 256 * 2);
    __bf16* Bp1l = (__bf16*)alloc((size_t)512 * 256 * 2);
    __bf16* Bp2h = (__bf16*)alloc((size_t)256 * 320 * 2);
    __bf16* Bp2l = (__bf16*)alloc((size_t)256 * 320 * 2);

    const int NB = (N + 255) / 256;

    // ---- CSR build ----
    hipMemsetAsync(cnt, 0, (size_t)N * 4, stream);
    hist_kernel<<<(E + 255) / 256, 256, 0, stream>>>(dst, cnt, E);
    scan_blk<<<NB, 256, 0, stream>>>(cnt, incl, bsum, N);
    scan_top<<<1, 256, 0, stream>>>(bsum, boff, NB);
    scan_fix<<<NB, 256, 0, stream>>>(incl, boff, cnt, row_ptr, cursor, N);
    fill_kernel<<<(E + 255) / 256, 256, 0, stream>>>(src, dst, cursor, ssrc, sdst, E);

    // ---- weight split + fragment-major pack ----
    pack_b_kernel<<<(512 * 256 + 255) / 256, 256, 0, stream>>>(W1, Bp1h, Bp1l, 512, 256);
    pack_b_kernel<<<(256 * 320 + 255) / 256, 256, 0, stream>>>(W2, Bp2h, Bp2l, 256, 320);

    const int mblk = (N + 31) / 32;  // 1563

    // ---- layer 1 ----
    gemm_fused<256, 4, true><<<mblk, 256, 0, stream>>>(
        features, nullptr, nullptr, Bp1h, Bp1l, al1, ar1, feat1b, el1, er1, N, 512);
    edge_score_kernel<<<(E + 255) / 256, 256, 0, stream>>>(ssrc, sdst, el1, er1, pe, E);
    gat_aggregate<32, 0><<<(N + 3) / 4, 256, 0, stream>>>(
        feat1b, pe, row_ptr, ssrc, h_hi, h_lo, nullptr, N);

    // ---- layer 2 ----
    gemm_fused<320, 5, false><<<mblk, 256, 0, stream>>>(
        nullptr, h_hi, h_lo, Bp2h, Bp2l, al2, ar2, feat2b, el2, er2, N, 256);
    edge_score_kernel<<<(E + 255) / 256, 256, 0, stream>>>(ssrc, sdst, el2, er2, pe, E);
    gat_aggregate<40, 1><<<(N + 3) / 4, 256, 0, stream>>>(
        feat2b, pe, row_ptr, ssrc, nullptr, nullptr, (float*)d_out, N);
}